// Round 1
// 2131.620 us; speedup vs baseline: 1.2965x; 1.2965x over previous
//
#include <hip/hip_runtime.h>

#define FP_DIM 6144
#define RTOL 1e-5f
#define ATOL 1e-8f

// ---- fallback (fused) tile params ----
#define BM 128
#define BN 128
#define BK 32
#define LDT 40   // padded LDS row stride in halves (80 B)

typedef _Float16 half8 __attribute__((ext_vector_type(8)));
typedef float f32x4 __attribute__((ext_vector_type(4)));

typedef __attribute__((address_space(1))) const void* gas1_cvp;
typedef __attribute__((address_space(3))) void* as3_vp;

__device__ __forceinline__ void gll16(const _Float16* g, _Float16* l) {
  // async global->LDS, 16 B per lane, dest = wave-uniform base + lane*16
  __builtin_amdgcn_global_load_lds((gas1_cvp)g, (as3_vp)l, 16, 0, 0);
}

// ---------------- Kernel 1: prep queries ----------------
__global__ __launch_bounds__(256) void prep_q(
    const float* __restrict__ queries, const float* __restrict__ truths,
    _Float16* __restrict__ qn, float* __restrict__ tq, int* __restrict__ out) {
  const int q = blockIdx.x;
  const float* qr = queries + (size_t)q * FP_DIM;
  const float* tr = truths  + (size_t)q * FP_DIM;

  float sq = 0.f, st = 0.f, sd = 0.f;
  for (int j = threadIdx.x * 4; j < FP_DIM; j += 256 * 4) {
    float4 a = *(const float4*)(qr + j);
    float4 b = *(const float4*)(tr + j);
    sq += a.x * a.x + a.y * a.y + a.z * a.z + a.w * a.w;
    st += b.x * b.x + b.y * b.y + b.z * b.z + b.w * b.w;
    sd += a.x * b.x + a.y * b.y + a.z * b.z + a.w * b.w;
  }
  for (int d = 1; d < 64; d <<= 1) {
    sq += __shfl_xor(sq, d);
    st += __shfl_xor(st, d);
    sd += __shfl_xor(sd, d);
  }
  __shared__ float red[3][4];
  __shared__ float s_invq;
  const int wave = threadIdx.x >> 6;
  if ((threadIdx.x & 63) == 0) { red[0][wave] = sq; red[1][wave] = st; red[2][wave] = sd; }
  __syncthreads();
  if (threadIdx.x == 0) {
    float SQ = red[0][0] + red[0][1] + red[0][2] + red[0][3];
    float ST = red[1][0] + red[1][1] + red[1][2] + red[1][3];
    float SD = red[2][0] + red[2][1] + red[2][2] + red[2][3];
    float nq = fmaxf(sqrtf(SQ), 1e-12f);
    float nt = fmaxf(sqrtf(ST), 1e-12f);
    float th = SD / (nq * nt);
    tq[q] = th - (ATOL + RTOL * fabsf(th));
    out[q] = -1;                       // counts are (#ge) - 1
    s_invq = 1.0f / nq;
  }
  __syncthreads();
  const float invq = s_invq;
  _Float16* qd = qn + (size_t)q * FP_DIM;
  for (int j = threadIdx.x * 4; j < FP_DIM; j += 256 * 4) {
    float4 a = *(const float4*)(qr + j);
    union { _Float16 h[4]; uint2 u; } pk;
    pk.h[0] = (_Float16)(a.x * invq);
    pk.h[1] = (_Float16)(a.y * invq);
    pk.h[2] = (_Float16)(a.z * invq);
    pk.h[3] = (_Float16)(a.w * invq);
    *(uint2*)(qd + j) = pk.u;
  }
}

// ---------------- Kernel 2a: convert data -> fp16 + inv-norms ----------------
// One block per (padded) row. Row stays in registers: load 24 floats, ssq on
// the side, convert+write immediately (no dependency on the reduction).
__global__ __launch_bounds__(256) void conv_a(
    const float* __restrict__ data, _Float16* __restrict__ A16,
    float* __restrict__ invn, int ND) {
  const int row = blockIdx.x;
  const int t = threadIdx.x;
  _Float16* dst = A16 + (size_t)row * FP_DIM;

  if (row >= ND) {                       // zero-fill pad rows
    uint4 z = {0u, 0u, 0u, 0u};
    for (int c = t; c < FP_DIM / 8; c += 256) *(uint4*)(dst + c * 8) = z;
    if (t == 0) invn[row] = 0.f;
    return;
  }

  const float* src = data + (size_t)row * FP_DIM;
  float ssq = 0.f;
#pragma unroll
  for (int p = 0; p < 3; ++p) {
    const int base = (t + p * 256) * 8;
    float4 a = *(const float4*)(src + base);
    float4 b = *(const float4*)(src + base + 4);
    ssq += a.x * a.x + a.y * a.y + a.z * a.z + a.w * a.w;
    ssq += b.x * b.x + b.y * b.y + b.z * b.z + b.w * b.w;
    union { _Float16 h[8]; uint4 u; } pk;
    pk.h[0] = (_Float16)a.x; pk.h[1] = (_Float16)a.y;
    pk.h[2] = (_Float16)a.z; pk.h[3] = (_Float16)a.w;
    pk.h[4] = (_Float16)b.x; pk.h[5] = (_Float16)b.y;
    pk.h[6] = (_Float16)b.z; pk.h[7] = (_Float16)b.w;
    *(uint4*)(dst + base) = pk.u;
  }
  for (int d = 1; d < 64; d <<= 1) ssq += __shfl_xor(ssq, d);
  __shared__ float red[4];
  if ((t & 63) == 0) red[t >> 6] = ssq;
  __syncthreads();
  if (t == 0) {
    float S = red[0] + red[1] + red[2] + red[3];
    invn[row] = 1.0f / fmaxf(sqrtf(S), 1e-12f);
  }
}

// ---------------- Kernel 2b: clean fp16 GEMM + count (m97 structure) ----------------
// 128x128 tile, K-step 64 as two 32-wide LDS planes (keeps 64B row stride),
// global_load_lds(16B) for both operands, 2-barrier loop, AGPR accumulate.
__global__ __launch_bounds__(256) void rank_gemm16(
    const _Float16* __restrict__ A16, const _Float16* __restrict__ qn,
    const float* __restrict__ tq, const float* __restrict__ invn,
    int* __restrict__ out, int ND) {
  __shared__ __align__(16) _Float16 sA[2][128 * 32];
  __shared__ __align__(16) _Float16 sB[2][128 * 32];
  __shared__ float sNrm[128];
  __shared__ int sCnt[128];

  const int t = threadIdx.x;
  const int n0 = blockIdx.x * 128;
  const int m0 = blockIdx.y * 128;
  const int wave = t >> 6, lane = t & 63;
  const int quad = lane >> 4, l16 = lane & 15;
  const int wm = (wave >> 1) * 64, wn = (wave & 1) * 64;

  f32x4 acc[4][4];
#pragma unroll
  for (int i = 0; i < 4; ++i)
#pragma unroll
    for (int j = 0; j < 4; ++j) acc[i][j] = (f32x4){0.f, 0.f, 0.f, 0.f};

  if (t < 128) { sNrm[t] = invn[m0 + t]; sCnt[t] = 0; }

  // staging addresses: per wave-call, 16 rows x 64 B, lane = row*(4) + 16B-chunk
  const int srow = lane >> 2;
  const int sch = (lane & 3) * 8;  // halves
  const _Float16* ag = A16 + (size_t)(m0 + wave * 32 + srow) * FP_DIM + sch;
  const _Float16* bg = qn  + (size_t)(n0 + wave * 32 + srow) * FP_DIM + sch;

  for (int k0 = 0; k0 < FP_DIM; k0 += 64) {
    __syncthreads();
#pragma unroll
    for (int pl = 0; pl < 2; ++pl) {
      const int ko = k0 + pl * 32;
      gll16(ag + ko,               &sA[pl][(wave * 32) * 32]);
      gll16(ag + 16 * FP_DIM + ko, &sA[pl][(wave * 32 + 16) * 32]);
      gll16(bg + ko,               &sB[pl][(wave * 32) * 32]);
      gll16(bg + 16 * FP_DIM + ko, &sB[pl][(wave * 32 + 16) * 32]);
    }
    __syncthreads();   // compiler emits vmcnt(0) drain here
#pragma unroll
    for (int pl = 0; pl < 2; ++pl) {
      half8 af[4], bf[4];
#pragma unroll
      for (int i = 0; i < 4; ++i)
        af[i] = *(const half8*)(&sA[pl][(wm + i * 16 + l16) * 32 + quad * 8]);
#pragma unroll
      for (int j = 0; j < 4; ++j)
        bf[j] = *(const half8*)(&sB[pl][(wn + j * 16 + l16) * 32 + quad * 8]);
#pragma unroll
      for (int i = 0; i < 4; ++i)
#pragma unroll
        for (int j = 0; j < 4; ++j)
          acc[i][j] = __builtin_amdgcn_mfma_f32_16x16x32_f16(af[i], bf[j], acc[i][j], 0, 0, 0);
    }
  }

  // epilogue: D layout (16x16): row(m) = quad*4 + reg, col(n) = lane&15
#pragma unroll
  for (int j = 0; j < 4; ++j) {
    const float tv = tq[n0 + wn + j * 16 + l16];
    int cc = 0;
#pragma unroll
    for (int i = 0; i < 4; ++i) {
      const int rbase = wm + i * 16 + quad * 4;
#pragma unroll
      for (int r = 0; r < 4; ++r) {
        const int row = rbase + r;
        if (m0 + row < ND) {
          const float qp = acc[i][j][r] * sNrm[row];
          cc += (qp >= tv) ? 1 : 0;
        }
      }
    }
    cc += __shfl_xor(cc, 16);
    cc += __shfl_xor(cc, 32);
    if (lane < 16) atomicAdd(&sCnt[wn + j * 16 + l16], cc);
  }
  __syncthreads();
  if (t < 128) atomicAdd(&out[n0 + t], sCnt[t]);
}

// ---------------- Fallback: fused GEMM + count (previous best, unchanged) ----------------
__global__ __launch_bounds__(256) void rank_gemm(
    const float* __restrict__ data, const _Float16* __restrict__ qn,
    const float* __restrict__ tq, int* __restrict__ out, int ND) {
  __shared__ __align__(16) _Float16 sA[BM * LDT];
  __shared__ __align__(16) _Float16 sB[BN * LDT];
  __shared__ float sNrm[BM];
  __shared__ int sCnt[BN];

  const int t = threadIdx.x;
  const int n0 = blockIdx.x * BN;
  const int m0 = blockIdx.y * BM;

  const int wave = t >> 6, lane = t & 63;
  const int quad = lane >> 4, l16 = lane & 15;
  const int wm = (wave >> 1) * 64, wn = (wave & 1) * 64;

  f32x4 acc[4][4];
#pragma unroll
  for (int i = 0; i < 4; ++i)
#pragma unroll
    for (int j = 0; j < 4; ++j) acc[i][j] = (f32x4){0.f, 0.f, 0.f, 0.f};

  float ssq[4] = {0.f, 0.f, 0.f, 0.f};

  const int ar = t >> 3;
  const int ac = (t & 7) * 4;
  const int br = t >> 2;
  const int bc = (t & 3) * 8;

  for (int k0 = 0; k0 < FP_DIM; k0 += BK) {
    __syncthreads();
#pragma unroll
    for (int p = 0; p < 4; ++p) {
      const int row = p * 32 + ar;
      const int gr = m0 + row;
      float4 v = {0.f, 0.f, 0.f, 0.f};
      if (gr < ND) v = *(const float4*)(data + (size_t)gr * FP_DIM + k0 + ac);
      ssq[p] += v.x * v.x + v.y * v.y + v.z * v.z + v.w * v.w;
      union { _Float16 h[4]; uint2 u; } pk;
      pk.h[0] = (_Float16)v.x; pk.h[1] = (_Float16)v.y;
      pk.h[2] = (_Float16)v.z; pk.h[3] = (_Float16)v.w;
      *(uint2*)(sA + row * LDT + ac) = pk.u;
    }
#pragma unroll
    for (int p = 0; p < 2; ++p) {
      const int row = p * 64 + br;
      *(uint4*)(sB + row * LDT + bc) =
          *(const uint4*)(qn + (size_t)(n0 + row) * FP_DIM + k0 + bc);
    }
    __syncthreads();

    half8 af[4], bf[4];
#pragma unroll
    for (int i = 0; i < 4; ++i)
      af[i] = *(const half8*)(sA + (wm + i * 16 + l16) * LDT + quad * 8);
#pragma unroll
    for (int j = 0; j < 4; ++j)
      bf[j] = *(const half8*)(sB + (wn + j * 16 + l16) * LDT + quad * 8);
#pragma unroll
    for (int i = 0; i < 4; ++i)
#pragma unroll
      for (int j = 0; j < 4; ++j)
        acc[i][j] = __builtin_amdgcn_mfma_f32_16x16x32_f16(af[i], bf[j], acc[i][j], 0, 0, 0);
  }

#pragma unroll
  for (int p = 0; p < 4; ++p) {
    float s = ssq[p];
    s += __shfl_xor(s, 1);
    s += __shfl_xor(s, 2);
    s += __shfl_xor(s, 4);
    if ((t & 7) == 0) sNrm[p * 32 + ar] = 1.0f / fmaxf(sqrtf(s), 1e-12f);
  }
  if (t < BN) sCnt[t] = 0;
  __syncthreads();

#pragma unroll
  for (int j = 0; j < 4; ++j) {
    const float tv = tq[n0 + wn + j * 16 + l16];
    int cc = 0;
#pragma unroll
    for (int i = 0; i < 4; ++i) {
      const int rbase = wm + i * 16 + quad * 4;
#pragma unroll
      for (int r = 0; r < 4; ++r) {
        const int row = rbase + r;
        if (m0 + row < ND) {
          const float qp = acc[i][j][r] * sNrm[row];
          cc += (qp >= tv) ? 1 : 0;
        }
      }
    }
    cc += __shfl_xor(cc, 16);
    cc += __shfl_xor(cc, 32);
    if (lane < 16) atomicAdd(&sCnt[wn + j * 16 + l16], cc);
  }
  __syncthreads();
  if (t < BN) atomicAdd(&out[n0 + t], sCnt[t]);
}

extern "C" void kernel_launch(void* const* d_in, const int* in_sizes, int n_in,
                              void* d_out, int out_size, void* d_ws, size_t ws_size,
                              hipStream_t stream) {
  const float* data    = (const float*)d_in[0];
  const float* queries = (const float*)d_in[1];
  const float* truths  = (const float*)d_in[2];
  const int ND = in_sizes[0] / FP_DIM;   // 50000
  const int Q  = in_sizes[1] / FP_DIM;   // 512
  const int NDpad = ((ND + 127) / 128) * 128;

  // workspace layout
  _Float16* qn = (_Float16*)d_ws;
  size_t off = (size_t)Q * FP_DIM * 2;
  float* tq = (float*)((char*)d_ws + off);
  off += (((size_t)Q * 4 + 255) & ~(size_t)255);
  float* invn = (float*)((char*)d_ws + off);
  off += (((size_t)NDpad * 4 + 255) & ~(size_t)255);
  _Float16* A16 = (_Float16*)((char*)d_ws + off);
  const size_t need = off + (size_t)NDpad * FP_DIM * 2;

  int* out = (int*)d_out;

  prep_q<<<Q, 256, 0, stream>>>(queries, truths, qn, tq, out);

  if (ws_size >= need) {
    conv_a<<<NDpad, 256, 0, stream>>>(data, A16, invn, ND);
    dim3 grid(Q / 128, NDpad / 128);   // col-tiles fast => A-tile L3 reuse
    rank_gemm16<<<grid, 256, 0, stream>>>(A16, qn, tq, invn, out, ND);
  } else {
    dim3 grid(Q / BN, (ND + BM - 1) / BM);
    rank_gemm<<<grid, 256, 0, stream>>>(data, qn, tq, out, ND);
  }
}